// Round 5
// baseline (186.844 us; speedup 1.0000x reference)
//
#include <hip/hip_runtime.h>
#include <hip/hip_bf16.h>
#include <stdint.h>

// KAN layer: out[b,o] = sum_{i,k} basis(tanh(x[b,i]))[k] * coeffs[o,i,k]
// GEMM M=8192, N=512, K=4096.  cvt coeffs->Bt bf16 (ws) ; basis(x)->A (ws) ;
// gemm(A,Bt)->out in ONE pass over K (no split-K, no atomics).
// GEMM pipe balance per CU per K-tile (the R2->R5 change):
//   R2: LDS = 32KB wr + 64KB rd = 96KB ~ 1130cy  >> MFMA 620cy  (LDS-bound)
//   R5: B-frags load DIRECT global->VGPR (Bt 4MB = L2-resident/XCD): LDS
//       48KB ~ 565cy, L2-B 32KB ~ 546cy, MFMA 620cy -- three balanced pipes.
// A stays global_load_lds dbuf (2x16KB); B double-buffered in registers,
// statically unrolled x2 (no pointer-select -> no spills).

#define M_TOTAL 8192
#define N_DIM   512
#define K_DIM   4096
#define BM 128
#define BN 128
#define BK 64
#define NTILES (K_DIM / BK)   // 64

typedef __attribute__((ext_vector_type(8))) short short8;   // 8 x bf16
typedef __attribute__((ext_vector_type(4))) float f32x4;

typedef const __attribute__((address_space(1))) uint32_t ga_u32;
typedef __attribute__((address_space(3))) uint32_t ls_u32;

__device__ __forceinline__ void gload_lds16(const void* g, void* l) {
  // async global->LDS, 16B/lane; LDS dest = wave-uniform base + lane*16
  __builtin_amdgcn_global_load_lds((ga_u32*)(uintptr_t)g,
                                   (ls_u32*)(uint32_t)(uintptr_t)l, 16, 0, 0);
}

__device__ __forceinline__ uint32_t f2bf(float f) {
  uint32_t u = __builtin_bit_cast(uint32_t, f);
  return (u + 0x7FFFu + ((u >> 16) & 1u)) >> 16;
}

// cardinal cubic B-spline on uniform knots h=2/11; t=tanh(x) in (-1,1).
// 8 basis slots as 4xu32 packed bf16: w0..w3 land at slots c-3..c, rest 0.
__device__ __forceinline__ void basis_slots(float xv, uint32_t o[4]) {
  xv = fminf(15.f, fmaxf(-15.f, xv));
  float e  = __expf(2.0f * xv);
  float t  = (e - 1.0f) * __builtin_amdgcn_rcpf(e + 1.0f);
  float uf = (t + 1.0f) * 5.5f;            // /h
  int   c  = (int)uf;  c = c > 10 ? 10 : c;
  float u  = uf - (float)c;
  float u2 = u * u, u3 = u2 * u, om = 1.0f - u;
  float w0 = om * om * om * (1.0f / 6.0f);
  float w1 = (3.0f * u3 - 6.0f * u2 + 4.0f) * (1.0f / 6.0f);
  float w2 = (-3.0f * u3 + 3.0f * u2 + 3.0f * u + 1.0f) * (1.0f / 6.0f);
  float w3 = u3 * (1.0f / 6.0f);
  uint32_t p01 = f2bf(w0) | (f2bf(w1) << 16);
  uint32_t p23 = f2bf(w2) | (f2bf(w3) << 16);
  uint64_t W = (uint64_t)p01 | ((uint64_t)p23 << 32);
  int d = c - 3;                            // slot of w0, in [-3, 7]
  uint64_t lo = (d < 0) ? (W >> ((-d) * 16))
              : ((d < 4) ? (W << (d * 16)) : 0ull);
  uint64_t hi = (d <= 0) ? 0ull
              : ((d < 4) ? (W >> ((4 - d) * 16)) : (W << ((d - 4) * 16)));
  o[0] = (uint32_t)lo; o[1] = (uint32_t)(lo >> 32);
  o[2] = (uint32_t)hi; o[3] = (uint32_t)(hi >> 32);
}

// ---------------- basis kernel: one (b,i) per thread, 16B store --------------
__global__ __launch_bounds__(256) void basis_kernel(const float* __restrict__ x,
                                                    __hip_bfloat16* __restrict__ A,
                                                    int total) {
  int idx = blockIdx.x * 256 + threadIdx.x;
  if (idx >= total) return;
  uint32_t o[4];
  basis_slots(x[idx], o);
  reinterpret_cast<int4*>(A)[idx] = make_int4(o[0], o[1], o[2], o[3]);
}

// ---------------- coeff cast: [512][512][8] fp32 -> bf16 (== B^T[512][4096]) --
__global__ __launch_bounds__(256) void cvt_kernel(const float* __restrict__ c,
                                                  __hip_bfloat16* __restrict__ Bt,
                                                  int total8) {
  int idx = blockIdx.x * 256 + threadIdx.x;
  if (idx >= total8) return;
  const float4* cp = reinterpret_cast<const float4*>(c) + (size_t)idx * 2;
  float4 a = cp[0], b = cp[1];
  union { unsigned short us[8]; int4 v; } pk;
  pk.us[0] = (unsigned short)f2bf(a.x); pk.us[1] = (unsigned short)f2bf(a.y);
  pk.us[2] = (unsigned short)f2bf(a.z); pk.us[3] = (unsigned short)f2bf(a.w);
  pk.us[4] = (unsigned short)f2bf(b.x); pk.us[5] = (unsigned short)f2bf(b.y);
  pk.us[6] = (unsigned short)f2bf(b.z); pk.us[7] = (unsigned short)f2bf(b.w);
  reinterpret_cast<int4*>(Bt)[idx] = pk.v;
}

// ---------------- GEMM: C[m,n] = sum_k A[m,k]*Bt[n,k] ------------------------
__global__ __launch_bounds__(256) void gemm_kernel(
    const __hip_bfloat16* __restrict__ A,   // [8192][4096]
    const __hip_bfloat16* __restrict__ Bt,  // [512][4096]
    float* __restrict__ C) {                // [8192][512]
  __shared__ __hip_bfloat16 lds[2 * BM * BK];   // A only: 2 x 16KB

  const int tid   = threadIdx.x;
  const int wid   = tid >> 6;
  const int lane  = tid & 63;
  const int quad  = lane >> 4;
  const int l16   = lane & 15;
  const int waveM = wid >> 1;               // 0..1
  const int waveN = wid & 1;                // 0..1

  // XCD decode: each XCD owns 8 M-stripes x all 4 N-tiles; Bt (4MB) is
  // L2-resident per XCD, A-stripes stream through once.
  const int b  = blockIdx.x;
  const int q  = b >> 3;                    // 0..31
  const int mt = (b & 7) * 8 + (q >> 2);    // 0..63
  const int nt = q & 3;                     // 0..3
  const int m0 = mt * BM;
  const int n0 = nt * BN;

  // A staging: slot s -> (row, phys chunk p); source chunk cc = p ^ (row&7)
  uint32_t aGlob[4], sOff[4];
#pragma unroll
  for (int t = 0; t < 4; ++t) {
    int s = t * 256 + tid, row = s >> 3, p = s & 7, cc = p ^ (row & 7);
    sOff[t]  = (uint32_t)s * 16u;
    aGlob[t] = (uint32_t)(m0 + row) * K_DIM + (uint32_t)cc * 8u;
  }

  // A fragment read offsets within a buffer
  uint32_t aOff[2][4];
#pragma unroll
  for (int kk = 0; kk < 2; ++kk) {
    int c = kk * 4 + quad;
#pragma unroll
    for (int mi = 0; mi < 4; ++mi) {
      int row = waveM * 64 + mi * 16 + l16;
      aOff[kk][mi] = (uint32_t)(row * 8 + (c ^ (row & 7))) * 16u;
    }
  }

  // B fragment global pointers: lane reads 16 contiguous bytes of one Bt row
  const __hip_bfloat16* bPtr[2][4];
#pragma unroll
  for (int kk = 0; kk < 2; ++kk)
#pragma unroll
    for (int ni = 0; ni < 4; ++ni) {
      int row = n0 + waveN * 64 + ni * 16 + l16;
      bPtr[kk][ni] = Bt + (size_t)row * K_DIM + kk * 32 + quad * 8;
    }

  char* ldsc = (char*)lds;
  char* buf0 = ldsc;
  char* buf1 = ldsc + BM * BK * 2;

  f32x4 acc[4][4];
#pragma unroll
  for (int mi = 0; mi < 4; ++mi)
#pragma unroll
    for (int ni = 0; ni < 4; ++ni)
      acc[mi][ni] = (f32x4){0.f, 0.f, 0.f, 0.f};

  short8 bR0[2][4], bR1[2][4];

#define STAGE_A(kt, buf)                                            \
  { _Pragma("unroll") for (int t = 0; t < 4; ++t)                   \
      gload_lds16(A + aGlob[t] + (kt), (buf) + sOff[t]); }
#define LOAD_B(dst, kt)                                             \
  { _Pragma("unroll") for (int kk = 0; kk < 2; ++kk)                \
      _Pragma("unroll") for (int ni = 0; ni < 4; ++ni)              \
        dst[kk][ni] = *reinterpret_cast<const short8*>(bPtr[kk][ni] + (kt)); }
#define COMPUTE(buf, bR)                                            \
  { _Pragma("unroll") for (int kk = 0; kk < 2; ++kk) {              \
      short8 af[4];                                                 \
      _Pragma("unroll") for (int mi = 0; mi < 4; ++mi)              \
        af[mi] = *reinterpret_cast<const short8*>((buf) + aOff[kk][mi]); \
      _Pragma("unroll") for (int mi = 0; mi < 4; ++mi)              \
        _Pragma("unroll") for (int ni = 0; ni < 4; ++ni)            \
          acc[mi][ni] = __builtin_amdgcn_mfma_f32_16x16x32_bf16(    \
              af[mi], bR[kk][ni], acc[mi][ni], 0, 0, 0); } }

  // prologue
  STAGE_A(0, buf0);
  LOAD_B(bR0, 0);

  for (int it = 0; it < NTILES; it += 2) {
    __syncthreads();                        // A tile it resident in buf0
    if (it + 1 < NTILES) {
      STAGE_A((uint32_t)(it + 1) * BK, buf1);
      LOAD_B(bR1, (it + 1) * BK);
    }
    COMPUTE(buf0, bR0);
    __syncthreads();                        // A tile it+1 resident in buf1
    if (it + 2 < NTILES) {
      STAGE_A((uint32_t)(it + 2) * BK, buf0);
      LOAD_B(bR0, (it + 2) * BK);
    }
    COMPUTE(buf1, bR1);
  }

  // epilogue: D row = quad*4 + r, col = l16 (m89/m91-verified C/D layout)
#pragma unroll
  for (int mi = 0; mi < 4; ++mi) {
#pragma unroll
    for (int ni = 0; ni < 4; ++ni) {
      int col = n0 + waveN * 64 + ni * 16 + l16;
#pragma unroll
      for (int r = 0; r < 4; ++r) {
        int row = m0 + waveM * 64 + mi * 16 + quad * 4 + r;
        C[(size_t)row * N_DIM + col] = acc[mi][ni][r];
      }
    }
  }
}

extern "C" void kernel_launch(void* const* d_in, const int* in_sizes, int n_in,
                              void* d_out, int out_size, void* d_ws, size_t ws_size,
                              hipStream_t stream) {
  const float* x    = (const float*)d_in[0];   // [8192,512]
  const float* coef = (const float*)d_in[1];   // [512,512,8]
  float* out = (float*)d_out;                  // [8192,512]

  __hip_bfloat16* Bt = (__hip_bfloat16*)d_ws;                       // 4 MB
  __hip_bfloat16* A  = (__hip_bfloat16*)((char*)d_ws + (size_t)4 * 1024 * 1024);
  // A = 64 MB; ws is ~268 MB (observed via harness poison fill), so it fits.

  const int total8 = N_DIM * K_DIM / 8;        // 262144
  cvt_kernel<<<(total8 + 255) / 256, 256, 0, stream>>>(coef, Bt, total8);

  const int total = M_TOTAL * 512;             // (b,i) pairs
  basis_kernel<<<total / 256, 256, 0, stream>>>(x, A, total);

  gemm_kernel<<<(M_TOTAL / BM) * (N_DIM / BN), 256, 0, stream>>>(A, Bt, out);
}

// Round 6
// 123.064 us; speedup vs baseline: 1.5183x; 1.5183x over previous
//
#include <hip/hip_runtime.h>
#include <hip/hip_bf16.h>
#include <stdint.h>

// KAN layer: out[b,o] = sum_{i,k} basis(tanh(x[b,i]))[k] * coeffs[o,i,k]
// GEMM M=8192, N=512, K=4096.  cvt coeffs->Bt bf16 (ws) ; basis(x)->A (ws) ;
// gemm(A,Bt)->out single pass over K.
// R5 lesson: per-lane global B-frag loads are a 64-line gather -> revert; both
// operands stage via coalesced global_load_lds.  R2 (61us) was 1 wave/SIMD
// latency-bound (grid 256 = 1 block/CU, 4 waves).  R6: SAME 128x128 tile +
// dbuf LDS, but 512 threads = 8 waves (2x4, wave tile 64x32) -> 2 waves/SIMD
// hides LDS/staging latency; per-tile LDS traffic unchanged.

#define M_TOTAL 8192
#define N_DIM   512
#define K_DIM   4096
#define BM 128
#define BN 128
#define BK 64
#define NTILES (K_DIM / BK)              // 64
#define BUF_BYTES ((BM + BN) * BK * 2)   // 32 KB per LDS buffer

typedef __attribute__((ext_vector_type(8))) short short8;   // 8 x bf16
typedef __attribute__((ext_vector_type(4))) float f32x4;

typedef const __attribute__((address_space(1))) uint32_t ga_u32;
typedef __attribute__((address_space(3))) uint32_t ls_u32;

__device__ __forceinline__ void gload_lds16(const void* g, void* l) {
  // async global->LDS, 16B/lane; LDS dest = wave-uniform base + lane*16
  __builtin_amdgcn_global_load_lds((ga_u32*)(uintptr_t)g,
                                   (ls_u32*)(uint32_t)(uintptr_t)l, 16, 0, 0);
}

__device__ __forceinline__ uint32_t f2bf(float f) {
  uint32_t u = __builtin_bit_cast(uint32_t, f);
  return (u + 0x7FFFu + ((u >> 16) & 1u)) >> 16;
}

// cardinal cubic B-spline on uniform knots h=2/11; t=tanh(x) in (-1,1).
// 8 basis slots as 4xu32 packed bf16: w0..w3 land at slots c-3..c, rest 0.
__device__ __forceinline__ void basis_slots(float xv, uint32_t o[4]) {
  xv = fminf(15.f, fmaxf(-15.f, xv));
  float e  = __expf(2.0f * xv);
  float t  = (e - 1.0f) * __builtin_amdgcn_rcpf(e + 1.0f);
  float uf = (t + 1.0f) * 5.5f;            // /h
  int   c  = (int)uf;  c = c > 10 ? 10 : c;
  float u  = uf - (float)c;
  float u2 = u * u, u3 = u2 * u, om = 1.0f - u;
  float w0 = om * om * om * (1.0f / 6.0f);
  float w1 = (3.0f * u3 - 6.0f * u2 + 4.0f) * (1.0f / 6.0f);
  float w2 = (-3.0f * u3 + 3.0f * u2 + 3.0f * u + 1.0f) * (1.0f / 6.0f);
  float w3 = u3 * (1.0f / 6.0f);
  uint32_t p01 = f2bf(w0) | (f2bf(w1) << 16);
  uint32_t p23 = f2bf(w2) | (f2bf(w3) << 16);
  uint64_t W = (uint64_t)p01 | ((uint64_t)p23 << 32);
  int d = c - 3;                            // slot of w0, in [-3, 7]
  uint64_t lo = (d < 0) ? (W >> ((-d) * 16))
              : ((d < 4) ? (W << (d * 16)) : 0ull);
  uint64_t hi = (d <= 0) ? 0ull
              : ((d < 4) ? (W >> ((4 - d) * 16)) : (W << ((d - 4) * 16)));
  o[0] = (uint32_t)lo; o[1] = (uint32_t)(lo >> 32);
  o[2] = (uint32_t)hi; o[3] = (uint32_t)(hi >> 32);
}

// ---------------- basis kernel: one (b,i) per thread, 16B store --------------
__global__ __launch_bounds__(256) void basis_kernel(const float* __restrict__ x,
                                                    __hip_bfloat16* __restrict__ A,
                                                    int total) {
  int idx = blockIdx.x * 256 + threadIdx.x;
  if (idx >= total) return;
  uint32_t o[4];
  basis_slots(x[idx], o);
  reinterpret_cast<int4*>(A)[idx] = make_int4(o[0], o[1], o[2], o[3]);
}

// ---------------- coeff cast: [512][512][8] fp32 -> bf16 (== B^T[512][4096]) --
__global__ __launch_bounds__(256) void cvt_kernel(const float* __restrict__ c,
                                                  __hip_bfloat16* __restrict__ Bt,
                                                  int total8) {
  int idx = blockIdx.x * 256 + threadIdx.x;
  if (idx >= total8) return;
  const float4* cp = reinterpret_cast<const float4*>(c) + (size_t)idx * 2;
  float4 a = cp[0], b = cp[1];
  union { unsigned short us[8]; int4 v; } pk;
  pk.us[0] = (unsigned short)f2bf(a.x); pk.us[1] = (unsigned short)f2bf(a.y);
  pk.us[2] = (unsigned short)f2bf(a.z); pk.us[3] = (unsigned short)f2bf(a.w);
  pk.us[4] = (unsigned short)f2bf(b.x); pk.us[5] = (unsigned short)f2bf(b.y);
  pk.us[6] = (unsigned short)f2bf(b.z); pk.us[7] = (unsigned short)f2bf(b.w);
  reinterpret_cast<int4*>(Bt)[idx] = pk.v;
}

// ---------------- GEMM: C[m,n] = sum_k A[m,k]*Bt[n,k] ------------------------
// 512 thr = 8 waves, wave grid 2(M) x 4(N), wave tile 64x32 (4x2 frags).
__global__ __launch_bounds__(512) void gemm_kernel(
    const __hip_bfloat16* __restrict__ A,   // [8192][4096]
    const __hip_bfloat16* __restrict__ Bt,  // [512][4096]
    float* __restrict__ C) {                // [8192][512]
  __shared__ __hip_bfloat16 lds[2 * (BM + BN) * BK];   // 64 KB

  const int tid   = threadIdx.x;
  const int wid   = tid >> 6;               // 0..7
  const int lane  = tid & 63;
  const int quad  = lane >> 4;
  const int l16   = lane & 15;
  const int waveM = wid >> 2;               // 0..1
  const int waveN = wid & 3;                // 0..3

  // XCD decode: each XCD owns 8 M-stripes x all 4 N-tiles; Bt (4MB) stays
  // L2-resident per XCD, A-stripes stream through once.
  const int b  = blockIdx.x;
  const int q  = b >> 3;                    // 0..31
  const int mt = (b & 7) * 8 + (q >> 2);    // 0..63
  const int nt = q & 3;                     // 0..3
  const int m0 = mt * BM;
  const int n0 = nt * BN;

  // staging: slot s -> (row, phys chunk p); source chunk cc = p ^ (row&7)
  // A: slots [0,1024) -> 16KB at buf+0 ; B: slots [0,1024) -> 16KB at buf+16K
  uint32_t aGlob[2], bGlob[2], sOff[2];
#pragma unroll
  for (int t = 0; t < 2; ++t) {
    int s = t * 512 + tid, row = s >> 3, p = s & 7, cc = p ^ (row & 7);
    sOff[t]  = (uint32_t)s * 16u;
    aGlob[t] = (uint32_t)(m0 + row) * K_DIM + (uint32_t)cc * 8u;
    bGlob[t] = (uint32_t)(n0 + row) * K_DIM + (uint32_t)cc * 8u;
  }

  // fragment read offsets within a buffer (A at +0, B at +16KB)
  uint32_t aOff[2][4], bOff[2][2];
#pragma unroll
  for (int kk = 0; kk < 2; ++kk) {
    int c = kk * 4 + quad;
#pragma unroll
    for (int mi = 0; mi < 4; ++mi) {
      int row = waveM * 64 + mi * 16 + l16;
      aOff[kk][mi] = (uint32_t)(row * 8 + (c ^ (row & 7))) * 16u;
    }
#pragma unroll
    for (int ni = 0; ni < 2; ++ni) {
      int row = waveN * 32 + ni * 16 + l16;
      bOff[kk][ni] = 16384u + (uint32_t)(row * 8 + (c ^ (row & 7))) * 16u;
    }
  }

  char* ldsc = (char*)lds;

  f32x4 acc[4][2];
#pragma unroll
  for (int mi = 0; mi < 4; ++mi)
#pragma unroll
    for (int ni = 0; ni < 2; ++ni)
      acc[mi][ni] = (f32x4){0.f, 0.f, 0.f, 0.f};

  // prologue: stage tile 0 into buffer 0
#pragma unroll
  for (int t = 0; t < 2; ++t) {
    gload_lds16(A + aGlob[t], ldsc + sOff[t]);
    gload_lds16(Bt + bGlob[t], ldsc + 16384 + sOff[t]);
  }

  for (int it = 0; it < NTILES; ++it) {
    const int cur = it & 1;
    char* bufc = ldsc + cur * BUF_BYTES;
    __syncthreads();                        // staging for tile it drained
    if (it + 1 < NTILES) {                  // stage it+1 under compute of it
      char* bufn = ldsc + (1 - cur) * BUF_BYTES;
      uint32_t kt = (uint32_t)(it + 1) * BK;
#pragma unroll
      for (int t = 0; t < 2; ++t) {
        gload_lds16(A + aGlob[t] + kt, bufn + sOff[t]);
        gload_lds16(Bt + bGlob[t] + kt, bufn + 16384 + sOff[t]);
      }
    }
#pragma unroll
    for (int kk = 0; kk < 2; ++kk) {
      short8 af[4], bf[2];
#pragma unroll
      for (int mi = 0; mi < 4; ++mi)
        af[mi] = *reinterpret_cast<const short8*>(bufc + aOff[kk][mi]);
#pragma unroll
      for (int ni = 0; ni < 2; ++ni)
        bf[ni] = *reinterpret_cast<const short8*>(bufc + bOff[kk][ni]);
#pragma unroll
      for (int mi = 0; mi < 4; ++mi)
#pragma unroll
        for (int ni = 0; ni < 2; ++ni)
          acc[mi][ni] = __builtin_amdgcn_mfma_f32_16x16x32_bf16(
              af[mi], bf[ni], acc[mi][ni], 0, 0, 0);
    }
  }

  // epilogue: D row = quad*4 + r, col = l16 (m89/m91-verified C/D layout)
#pragma unroll
  for (int mi = 0; mi < 4; ++mi) {
#pragma unroll
    for (int ni = 0; ni < 2; ++ni) {
      int col = n0 + waveN * 32 + ni * 16 + l16;
#pragma unroll
      for (int r = 0; r < 4; ++r) {
        int row = m0 + waveM * 64 + mi * 16 + quad * 4 + r;
        C[(size_t)row * N_DIM + col] = acc[mi][ni][r];
      }
    }
  }
}

extern "C" void kernel_launch(void* const* d_in, const int* in_sizes, int n_in,
                              void* d_out, int out_size, void* d_ws, size_t ws_size,
                              hipStream_t stream) {
  const float* x    = (const float*)d_in[0];   // [8192,512]
  const float* coef = (const float*)d_in[1];   // [512,512,8]
  float* out = (float*)d_out;                  // [8192,512]

  __hip_bfloat16* Bt = (__hip_bfloat16*)d_ws;                       // 4 MB
  __hip_bfloat16* A  = (__hip_bfloat16*)((char*)d_ws + (size_t)4 * 1024 * 1024);
  // A = 64 MB; ws is ~268 MB (observed via harness poison fill), fits.

  const int total8 = N_DIM * K_DIM / 8;        // 262144
  cvt_kernel<<<(total8 + 255) / 256, 256, 0, stream>>>(coef, Bt, total8);

  const int total = M_TOTAL * 512;             // (b,i) pairs
  basis_kernel<<<total / 256, 256, 0, stream>>>(x, A, total);

  gemm_kernel<<<(M_TOTAL / BM) * (N_DIM / BN), 512, 0, stream>>>(A, Bt, out);
}

// Round 7
// 119.838 us; speedup vs baseline: 1.5591x; 1.0269x over previous
//
#include <hip/hip_runtime.h>
#include <hip/hip_bf16.h>
#include <stdint.h>

// KAN layer: out[b,o] = sum_{i,k} basis(tanh(x[b,i]))[k] * coeffs[o,i,k]
// GEMM M=8192, N=512, K=4096.  cvt coeffs->Bt bf16 (ws) ; basis(x)->A (ws) ;
// gemm(A,Bt)->out.
// R6 post-mortem: 8 waves of 64x32 tiles -> LDS reads 96KB/tile (A-frags x4
// redundant, B x2) + 32KB staging = 128KB ~ 1500cy >> MFMA 620cy: LDS-BW wall.
// R7: 8 waves = 2x2 of 64x64 wave tiles x 2-way in-block K-split (each K-group
// has its own dbuf arena over half of K). Reads/wave-iter = (64+64)*32*2 = 8KB
// -> aggregate LDS 96KB/tile (-25%), same 2 waves/SIMD. Pair-sum epilogue via
// LDS once at the end (~1 tile's worth of traffic, amortized over 64 tiles).

#define M_TOTAL 8192
#define N_DIM   512
#define K_DIM   4096
#define BM 128
#define BN 128
#define BK 64
#define NT_HALF 32          // K-tiles per K-group (2048/64)
#define GRP_LDS 65536       // per-group arena: 2 buffers
#define BUF_HALF 32768      // one buffer: A 16KB + B 16KB

typedef __attribute__((ext_vector_type(8))) short short8;   // 8 x bf16
typedef __attribute__((ext_vector_type(4))) float f32x4;

typedef const __attribute__((address_space(1))) uint32_t ga_u32;
typedef __attribute__((address_space(3))) uint32_t ls_u32;

__device__ __forceinline__ void gload_lds16(const void* g, void* l) {
  // async global->LDS, 16B/lane; LDS dest = wave-uniform base + lane*16
  __builtin_amdgcn_global_load_lds((ga_u32*)(uintptr_t)g,
                                   (ls_u32*)(uint32_t)(uintptr_t)l, 16, 0, 0);
}

__device__ __forceinline__ uint32_t f2bf(float f) {
  uint32_t u = __builtin_bit_cast(uint32_t, f);
  return (u + 0x7FFFu + ((u >> 16) & 1u)) >> 16;
}

// cardinal cubic B-spline on uniform knots h=2/11; t=tanh(x) in (-1,1).
// 8 basis slots as 4xu32 packed bf16: w0..w3 land at slots c-3..c, rest 0.
__device__ __forceinline__ void basis_slots(float xv, uint32_t o[4]) {
  xv = fminf(15.f, fmaxf(-15.f, xv));
  float e  = __expf(2.0f * xv);
  float t  = (e - 1.0f) * __builtin_amdgcn_rcpf(e + 1.0f);
  float uf = (t + 1.0f) * 5.5f;            // /h
  int   c  = (int)uf;  c = c > 10 ? 10 : c;
  float u  = uf - (float)c;
  float u2 = u * u, u3 = u2 * u, om = 1.0f - u;
  float w0 = om * om * om * (1.0f / 6.0f);
  float w1 = (3.0f * u3 - 6.0f * u2 + 4.0f) * (1.0f / 6.0f);
  float w2 = (-3.0f * u3 + 3.0f * u2 + 3.0f * u + 1.0f) * (1.0f / 6.0f);
  float w3 = u3 * (1.0f / 6.0f);
  uint32_t p01 = f2bf(w0) | (f2bf(w1) << 16);
  uint32_t p23 = f2bf(w2) | (f2bf(w3) << 16);
  uint64_t W = (uint64_t)p01 | ((uint64_t)p23 << 32);
  int d = c - 3;                            // slot of w0, in [-3, 7]
  uint64_t lo = (d < 0) ? (W >> ((-d) * 16))
              : ((d < 4) ? (W << (d * 16)) : 0ull);
  uint64_t hi = (d <= 0) ? 0ull
              : ((d < 4) ? (W >> ((4 - d) * 16)) : (W << ((d - 4) * 16)));
  o[0] = (uint32_t)lo; o[1] = (uint32_t)(lo >> 32);
  o[2] = (uint32_t)hi; o[3] = (uint32_t)(hi >> 32);
}

// ---------------- basis kernel: one (b,i) per thread, 16B store --------------
__global__ __launch_bounds__(256) void basis_kernel(const float* __restrict__ x,
                                                    __hip_bfloat16* __restrict__ A,
                                                    int total) {
  int idx = blockIdx.x * 256 + threadIdx.x;
  if (idx >= total) return;
  uint32_t o[4];
  basis_slots(x[idx], o);
  reinterpret_cast<int4*>(A)[idx] = make_int4(o[0], o[1], o[2], o[3]);
}

// ---------------- coeff cast: [512][512][8] fp32 -> bf16 (== B^T[512][4096]) --
__global__ __launch_bounds__(256) void cvt_kernel(const float* __restrict__ c,
                                                  __hip_bfloat16* __restrict__ Bt,
                                                  int total8) {
  int idx = blockIdx.x * 256 + threadIdx.x;
  if (idx >= total8) return;
  const float4* cp = reinterpret_cast<const float4*>(c) + (size_t)idx * 2;
  float4 a = cp[0], b = cp[1];
  union { unsigned short us[8]; int4 v; } pk;
  pk.us[0] = (unsigned short)f2bf(a.x); pk.us[1] = (unsigned short)f2bf(a.y);
  pk.us[2] = (unsigned short)f2bf(a.z); pk.us[3] = (unsigned short)f2bf(a.w);
  pk.us[4] = (unsigned short)f2bf(b.x); pk.us[5] = (unsigned short)f2bf(b.y);
  pk.us[6] = (unsigned short)f2bf(b.z); pk.us[7] = (unsigned short)f2bf(b.w);
  reinterpret_cast<int4*>(Bt)[idx] = pk.v;
}

// ---------------- GEMM: C[m,n] = sum_k A[m,k]*Bt[n,k] ------------------------
// 512 thr = 8 waves: kgrp = wid>>2 (K-half), 2x2 waves of 64x64 per group.
__global__ __launch_bounds__(512) void gemm_kernel(
    const __hip_bfloat16* __restrict__ A,   // [8192][4096]
    const __hip_bfloat16* __restrict__ Bt,  // [512][4096]
    float* __restrict__ C) {                // [8192][512]
  __shared__ char lds[2 * GRP_LDS];         // 128 KB

  const int tid   = threadIdx.x;
  const int wid   = tid >> 6;               // 0..7
  const int lane  = tid & 63;
  const int quad  = lane >> 4;
  const int l16   = lane & 15;
  const int kgrp  = wid >> 2;               // 0..1: K-half
  const int w2    = wid & 3;
  const int waveM = w2 >> 1, waveN = w2 & 1;
  const int tg    = tid & 255;              // thread-in-group

  // XCD decode: each XCD owns 8 M-stripes x all 4 N-tiles; Bt (4MB) stays
  // L2-resident per XCD, A-stripes stream through once.
  const int b  = blockIdx.x;
  const int q  = b >> 3;                    // 0..31
  const int mt = (b & 7) * 8 + (q >> 2);    // 0..63
  const int nt = q & 3;                     // 0..3
  const int m0 = mt * BM;
  const int n0 = nt * BN;

  char* grp = lds + kgrp * GRP_LDS;

  // staging: slot s -> (row, phys chunk p); source chunk cc = p ^ (row&7)
  uint32_t aGlob[4], bGlob[4], sOff[4];
#pragma unroll
  for (int t = 0; t < 4; ++t) {
    int s = t * 256 + tg, row = s >> 3, p = s & 7, cc = p ^ (row & 7);
    sOff[t]  = (uint32_t)s * 16u;
    aGlob[t] = (uint32_t)(m0 + row) * K_DIM + (uint32_t)cc * 8u
             + (uint32_t)kgrp * 2048u;
    bGlob[t] = (uint32_t)(n0 + row) * K_DIM + (uint32_t)cc * 8u
             + (uint32_t)kgrp * 2048u;
  }

  // fragment read offsets within a buffer (A at +0, B at +16KB)
  uint32_t aOff[2][4], bOff[2][4];
#pragma unroll
  for (int kk = 0; kk < 2; ++kk) {
    int c = kk * 4 + quad;
#pragma unroll
    for (int mi = 0; mi < 4; ++mi) {
      int row = waveM * 64 + mi * 16 + l16;
      aOff[kk][mi] = (uint32_t)(row * 8 + (c ^ (row & 7))) * 16u;
    }
#pragma unroll
    for (int ni = 0; ni < 4; ++ni) {
      int row = waveN * 64 + ni * 16 + l16;
      bOff[kk][ni] = 16384u + (uint32_t)(row * 8 + (c ^ (row & 7))) * 16u;
    }
  }

  f32x4 acc[4][4];
#pragma unroll
  for (int mi = 0; mi < 4; ++mi)
#pragma unroll
    for (int ni = 0; ni < 4; ++ni)
      acc[mi][ni] = (f32x4){0.f, 0.f, 0.f, 0.f};

  // prologue: stage tile 0 of this K-half into buffer 0
#pragma unroll
  for (int t = 0; t < 4; ++t) {
    gload_lds16(A + aGlob[t], grp + sOff[t]);
    gload_lds16(Bt + bGlob[t], grp + 16384 + sOff[t]);
  }

  for (int it = 0; it < NT_HALF; ++it) {
    const int cur = it & 1;
    char* bufc = grp + cur * BUF_HALF;
    __syncthreads();                        // staging for tile it drained
    if (it + 1 < NT_HALF) {                 // stage it+1 under compute of it
      char* bufn = grp + (1 - cur) * BUF_HALF;
      uint32_t kt = (uint32_t)(it + 1) * BK;
#pragma unroll
      for (int t = 0; t < 4; ++t) {
        gload_lds16(A + aGlob[t] + kt, bufn + sOff[t]);
        gload_lds16(Bt + bGlob[t] + kt, bufn + 16384 + sOff[t]);
      }
    }
#pragma unroll
    for (int kk = 0; kk < 2; ++kk) {
      short8 af[4], bf[4];
#pragma unroll
      for (int mi = 0; mi < 4; ++mi)
        af[mi] = *reinterpret_cast<const short8*>(bufc + aOff[kk][mi]);
#pragma unroll
      for (int ni = 0; ni < 4; ++ni)
        bf[ni] = *reinterpret_cast<const short8*>(bufc + bOff[kk][ni]);
#pragma unroll
      for (int mi = 0; mi < 4; ++mi)
#pragma unroll
        for (int ni = 0; ni < 4; ++ni)
          acc[mi][ni] = __builtin_amdgcn_mfma_f32_16x16x32_bf16(
              af[mi], bf[ni], acc[mi][ni], 0, 0, 0);
    }
  }

  // split-K pair reduction: group 1 parks partials, group 0 sums + stores
  __syncthreads();
  if (kgrp == 1) {
#pragma unroll
    for (int mi = 0; mi < 4; ++mi)
#pragma unroll
      for (int ni = 0; ni < 4; ++ni) {
        int f = mi * 4 + ni;
        *reinterpret_cast<f32x4*>(lds + w2 * 16384 + f * 1024 + lane * 16) =
            acc[mi][ni];
      }
  }
  __syncthreads();
  if (kgrp == 0) {
#pragma unroll
    for (int mi = 0; mi < 4; ++mi) {
#pragma unroll
      for (int ni = 0; ni < 4; ++ni) {
        int f = mi * 4 + ni;
        f32x4 other = *reinterpret_cast<f32x4*>(
            lds + w2 * 16384 + f * 1024 + lane * 16);
        f32x4 s = acc[mi][ni] + other;
        int col = n0 + waveN * 64 + ni * 16 + l16;
#pragma unroll
        for (int r = 0; r < 4; ++r) {
          int row = m0 + waveM * 64 + mi * 16 + quad * 4 + r;
          C[(size_t)row * N_DIM + col] = s[r];   // m89/m91 C/D layout
        }
      }
    }
  }
}

extern "C" void kernel_launch(void* const* d_in, const int* in_sizes, int n_in,
                              void* d_out, int out_size, void* d_ws, size_t ws_size,
                              hipStream_t stream) {
  const float* x    = (const float*)d_in[0];   // [8192,512]
  const float* coef = (const float*)d_in[1];   // [512,512,8]
  float* out = (float*)d_out;                  // [8192,512]

  __hip_bfloat16* Bt = (__hip_bfloat16*)d_ws;                       // 4 MB
  __hip_bfloat16* A  = (__hip_bfloat16*)((char*)d_ws + (size_t)4 * 1024 * 1024);
  // A = 64 MB; ws is ~268 MB (observed via harness poison fill), fits.

  const int total8 = N_DIM * K_DIM / 8;        // 262144
  cvt_kernel<<<(total8 + 255) / 256, 256, 0, stream>>>(coef, Bt, total8);

  const int total = M_TOTAL * 512;             // (b,i) pairs
  basis_kernel<<<total / 256, 256, 0, stream>>>(x, A, total);

  gemm_kernel<<<(M_TOTAL / BM) * (N_DIM / BN), 512, 0, stream>>>(A, Bt, out);
}